// Round 12
// baseline (312.218 us; speedup 1.0000x reference)
//
#include <hip/hip_runtime.h>
#include <math.h>

namespace {

constexpr int NQ  = 6000;   // fluid particles (queries)
constexpr int NB  = 3000;   // box particles
constexpr int K   = 80;     // neighbor cap
constexpr float RAD = 0.1125f;
constexpr float R2  = RAD * RAD;
constexpr float EPSF = 1e-12f;

constexpr int GS  = 8;           // grid dim (cell 0.125 >= RADIUS)
constexpr int NC  = GS*GS*GS;    // 512 cells
constexpr int NO  = 65 * 64;     // G row: 64 cells + 1 dense-skip col, O=64
constexpr int NBLK = (NQ + 3) / 4;            // gather3 blocks (4 queries each)
constexpr int NBLK8 = ((NBLK + 7) / 8) * 8;   // padded for XCD swizzle
constexpr int NG2  = (NQ + 1) / 2;            // gatherG blocks (2 q x 2 waves) = 3000

typedef __attribute__((ext_vector_type(8))) short bf16x8;
typedef __attribute__((ext_vector_type(4))) float f32x4;

__device__ __forceinline__ float sgn(float x) {
    return (x > 0.f) ? 1.f : ((x < 0.f) ? -1.f : 0.f);
}

__device__ __forceinline__ unsigned int bf16rne(float f) {
    unsigned int u = __float_as_uint(f);
    return (u + 0x7fffu + ((u >> 16) & 1u)) >> 16;   // round-to-nearest-even
}
__device__ __forceinline__ float bf16f(unsigned short u) {
    return __uint_as_float(((unsigned int)u) << 16);
}
__device__ __forceinline__ int cell_of(float x, float y, float z) {
    int cx = min(max((int)(x * (float)GS), 0), GS-1);
    int cy = min(max((int)(y * (float)GS), 0), GS-1);
    int cz = min(max((int)(z * (float)GS), 0), GS-1);
    return (cz*GS + cy)*GS + cx;
}

// ball->cube + trilinear coefs from raw delta (ddx = pj - q), store at slot
__device__ void coef_store(float ddx, float ddy, float ddz, int slot,
                           int* __restrict__ cells, float* __restrict__ coefs)
{
    float rx = ddx / RAD, ry = ddy / RAD, rz = ddz / RAD;
    float r2 = rx*rx + ry*ry + rz*rz;
    float w1 = 1.f - r2;
    float win = (w1 > 0.f) ? w1*w1*w1 : 0.f;   // clip((1-r2)^3, 0, 1)
    float norm = sqrtf(r2);
    float rxy2 = rx*rx + ry*ry;
    float xc, yc, zc;
    if (r2 < 1e-12f) {
        xc = yc = zc = 0.f;
    } else if (1.25f * rz * rz > rxy2) {
        float s = sqrtf(3.0f * norm / (norm + fabsf(rz) + EPSF));
        xc = s * rx; yc = s * ry; zc = sgn(rz) * norm;
    } else {
        float s = norm / sqrtf(rxy2 + EPSF);
        xc = s * rx; yc = s * ry; zc = 1.5f * rz * s;
    }
    float rxy = sqrtf(xc*xc + yc*yc);
    const float FP = (float)(4.0 / M_PI);
    float u, v;
    if (rxy < EPSF) {
        u = 0.f; v = 0.f;
    } else if (fabsf(xc) >= fabsf(yc)) {
        float sx = (fabsf(xc) < EPSF) ? EPSF : xc;
        u = sgn(xc) * rxy;
        v = u * FP * atanf(yc / sx);
    } else {
        float sy = (fabsf(yc) < EPSF) ? EPSF : yc;
        v = sgn(yc) * rxy;
        u = v * FP * atanf(xc / sy);
    }
    float gx = fminf(fmaxf((u  + 1.f) * 0.5f * 3.f, 0.f), 3.f);
    float gy = fminf(fmaxf((v  + 1.f) * 0.5f * 3.f, 0.f), 3.f);
    float gz = fminf(fmaxf((zc + 1.f) * 0.5f * 3.f, 0.f), 3.f);
    int ix = min((int)floorf(gx), 2);
    int iy = min((int)floorf(gy), 2);
    int iz = min((int)floorf(gz), 2);
    float tx = gx - (float)ix, ty = gy - (float)iy, tz = gz - (float)iz;
    cells[slot] = iz*16 + iy*4 + ix;
    float wx[2] = {1.f - tx, tx}, wy[2] = {1.f - ty, ty}, wz[2] = {1.f - tz, tz};
    float* cf = coefs + (size_t)slot * 8;
#pragma unroll
    for (int c = 0; c < 8; ++c)   // c = dx*4 + dy*2 + dz (python loop order)
        cf[c] = wx[c >> 2] * wy[(c >> 1) & 1] * wz[c & 1] * win;
}

// ---------------- grid build -------------------------------------------------
__global__ __launch_bounds__(512) void scan_kernel(
    const int* __restrict__ gcnt,
    int* __restrict__ gs_f, int* __restrict__ gs_b,
    int* __restrict__ cur_f, int* __restrict__ cur_b)
{
    __shared__ int tmp[NC];
    int tid = threadIdx.x;
#pragma unroll
    for (int a = 0; a < 2; ++a) {
        int cntv = gcnt[a*NC + tid];
        tmp[tid] = cntv;
        __syncthreads();
        for (int off = 1; off < NC; off <<= 1) {
            int v = (tid >= off) ? tmp[tid - off] : 0;
            __syncthreads();
            tmp[tid] += v;
            __syncthreads();
        }
        int* gsd = a ? gs_b : gs_f;
        int* cur = a ? cur_b : cur_f;
        int excl = tmp[tid] - cntv;
        gsd[tid] = excl;
        cur[tid] = excl;
        if (tid == NC - 1) gsd[NC] = tmp[tid];
        __syncthreads();
    }
}

__global__ __launch_bounds__(256) void scatter_pts_kernel(
    const float* __restrict__ pos, const float* __restrict__ box,
    int* __restrict__ cur_f, int* __restrict__ cur_b,
    float* __restrict__ spf, int* __restrict__ sif,
    float* __restrict__ spb, int* __restrict__ sib)
{
    int t = blockIdx.x * blockDim.x + threadIdx.x;
    if (t < NQ) {
        float x = pos[t*3], y = pos[t*3+1], z = pos[t*3+2];
        int dst = atomicAdd(&cur_f[cell_of(x,y,z)], 1);
        spf[dst*3] = x; spf[dst*3+1] = y; spf[dst*3+2] = z;
        sif[dst] = t;
    } else if (t < NQ + NB) {
        int b = t - NQ;
        float x = box[b*3], y = box[b*3+1], z = box[b*3+2];
        int dst = atomicAdd(&cur_b[cell_of(x,y,z)], 1);
        spb[dst*3] = x; spb[dst*3+1] = y; spb[dst*3+2] = z;
        sib[dst] = b;
    }
}

// -------- fused neighbor search + coef compute (one wave per query) ----------
__global__ __launch_bounds__(256) void nn2gc_kernel(
    const float* __restrict__ pos,
    const float* __restrict__ spf, const int* __restrict__ sif, const int* __restrict__ gsf,
    const float* __restrict__ spb, const int* __restrict__ sib, const int* __restrict__ gsb,
    int* __restrict__ f_cnt, int* __restrict__ f_idx, float* __restrict__ f_d2,
    int* __restrict__ f_cell, float* __restrict__ f_coef,
    int* __restrict__ b_cnt, int* __restrict__ b_idx, float* __restrict__ b_d2,
    int* __restrict__ b_cell, float* __restrict__ b_coef)
{
    int gw = (blockIdx.x * blockDim.x + threadIdx.x) >> 6;
    int lane = threadIdx.x & 63;
    if (gw >= 2 * NQ) return;
    bool isF = gw < NQ;
    int wid = isF ? gw : gw - NQ;
    const float* sp = isF ? spf : spb;
    const int*   si = isF ? sif : sib;
    const int*   gs = isF ? gsf : gsb;
    int*   cnt   = isF ? f_cnt  : b_cnt;
    int*   idxs  = isF ? f_idx  : b_idx;
    float* d2s   = isF ? f_d2   : b_d2;
    int*   cells = isF ? f_cell : b_cell;
    float* coefs = isF ? f_coef : b_coef;
    float qx = pos[wid*3+0], qy = pos[wid*3+1], qz = pos[wid*3+2];
    int cx = min(max((int)(qx * (float)GS), 0), GS-1);
    int cy = min(max((int)(qy * (float)GS), 0), GS-1);
    int cz = min(max((int)(qz * (float)GS), 0), GS-1);
    int x0 = max(cx-1, 0), x1 = min(cx+1, GS-1);
    int base = wid * K;
    int c = 0;
    for (int dz = -1; dz <= 1; ++dz) {
        int z = cz + dz; if ((unsigned)z >= (unsigned)GS) continue;
        for (int dy = -1; dy <= 1; ++dy) {
            int y = cy + dy; if ((unsigned)y >= (unsigned)GS) continue;
            int row = (z*GS + y)*GS;
            int s0 = gs[row + x0], s1 = gs[row + x1 + 1];
            for (int j0 = s0; j0 < s1; j0 += 64) {
                int ii = j0 + lane;
                float d2 = 1e30f; int oj = 0;
                float ddx = 0.f, ddy = 0.f, ddz = 0.f;
                if (ii < s1) {
                    oj = si[ii];
                    ddx = sp[ii*3+0]-qx; ddy = sp[ii*3+1]-qy; ddz = sp[ii*3+2]-qz;
                    d2 = ddx*ddx + ddy*ddy + ddz*ddz;
                    if (isF && oj == wid) d2 = 1e30f;
                }
                bool hit = d2 <= R2;
                unsigned long long m = __ballot(hit);
                int pc = __popcll(m);
                if (pc == 0) continue;
                if (c + pc <= K) {
                    if (hit) {
                        int p = c + __popcll(m & ((1ull << lane) - 1ull));
                        idxs[base + p] = oj;
                        d2s [base + p] = d2;
                        coef_store(ddx, ddy, ddz, base + p, cells, coefs);
                    }
                    c += pc;
                } else {
                    // rare overflow: keep the K nearest (top_k semantics)
                    while (m) {
                        int l = __ffsll((unsigned long long)m) - 1;
                        m &= m - 1ull;
                        float dd = __shfl(d2, l);
                        int jv = __shfl(oj, l);
                        float ax = __shfl(ddx, l), ay = __shfl(ddy, l), az = __shfl(ddz, l);
                        int slot = -1;
                        if (c < K) { slot = c; c++; }
                        else {
                            float mx = -1.f; int am = 0;
                            for (int s = 0; s < K; ++s) {
                                float v = d2s[base + s];
                                if (v > mx) { mx = v; am = s; }
                            }
                            if (dd < mx) slot = am;
                        }
                        if (slot >= 0 && lane == 0) {
                            idxs[base + slot] = jv;
                            d2s [base + slot] = dd;
                            coef_store(ax, ay, az, base + slot, cells, coefs);
                        }
                    }
                }
            }
        }
    }
    if (lane == 0) cnt[wid] = c;
}

// ------- small scatter (F in {3,4}): one WAVE per point, lane=(corner,feat) --
template<int F>
__device__ void scatter_small_dev(
    const float* __restrict__ feats,
    const int* __restrict__ cnt, const int* __restrict__ nidx,
    const int* __restrict__ ncell, const float* __restrict__ ncoef,
    float* __restrict__ Sg, int blk)
{
    __shared__ __align__(16) float S4[4][64 * F];
    int tid = threadIdx.x, lane = tid & 63, w = tid >> 6;
    int n = blk * 4 + w;
    if (n >= NQ) return;
    float* Sw = S4[w];
    for (int i = lane; i < 64 * F; i += 64) Sw[i] = 0.f;
    int cn = cnt[n];
    int kk2 = 64 + lane;
    int cb1 = (lane < cn) ? ncell[n*K + lane] : 0;
    int j1  = (lane < cn) ? nidx [n*K + lane] : 0;
    int cb2 = (kk2 < cn) ? ncell[n*K + kk2] : 0;
    int j2  = (kk2 < cn) ? nidx [n*K + kk2] : 0;
    int c = lane & 7, f = lane >> 3;
    bool fok = f < F;
    const float* coefG = ncoef + (size_t)n * K * 8;

    float wgt = 0.f, v = 0.f; int cb = 0;
    if (cn > 0) {
        int j = __shfl(j1, 0); cb = __shfl(cb1, 0);
        if (fok) { wgt = coefG[c]; v = feats[(size_t)j * F + f]; }
    }
    for (int kk = 0; kk < cn; ++kk) {
        float wn = 0.f, vn = 0.f; int cbn = 0;
        int k1n = kk + 1;
        if (k1n < cn) {
            int jn = (k1n < 64) ? __shfl(j1, k1n) : __shfl(j2, k1n - 64);
            cbn    = (k1n < 64) ? __shfl(cb1, k1n) : __shfl(cb2, k1n - 64);
            if (fok) { wn = coefG[k1n*8 + c]; vn = feats[(size_t)jn * F + f]; }
        }
        if (fok) {
            int cell = cb + (c & 1)*16 + ((c >> 1) & 1)*4 + (c >> 2);
            Sw[cell*F + f] += wgt * v;
        }
        wgt = wn; v = vn; cb = cbn;
    }
    float* row = Sg + (size_t)n * (64 * F);
    for (int i = lane; i < 16 * F; i += 64)
        ((float4*)row)[i] = ((const float4*)Sw)[i];
}

// merged layer-0 scatters: blocks [0,FB) = fluid F=4, [FB,2FB) = box F=3
__global__ __launch_bounds__(256) void scatter0_kernel(
    const float* __restrict__ ff,
    const int* __restrict__ f_cnt, const int* __restrict__ f_idx,
    const int* __restrict__ f_cell, const float* __restrict__ f_coef,
    const float* __restrict__ bfeat,
    const int* __restrict__ b_cnt, const int* __restrict__ b_idx,
    const int* __restrict__ b_cell, const float* __restrict__ b_coef,
    float* __restrict__ S_cf, float* __restrict__ S_co)
{
    constexpr int FB = (NQ + 3) / 4;
    if (blockIdx.x < FB)
        scatter_small_dev<4>(ff, f_cnt, f_idx, f_cell, f_coef, S_cf, blockIdx.x);
    else
        scatter_small_dev<3>(bfeat, b_cnt, b_idx, b_cell, b_coef, S_co, blockIdx.x - FB);
}

// ---- layer-0 dual GEMM, full-K per block, bias fused, writes x1 directly ----
__global__ __launch_bounds__(256) void gemm0_kernel(
    const float* __restrict__ S_co, const float* __restrict__ S_cf,
    const float* __restrict__ coW, const float* __restrict__ cfW,
    const float* __restrict__ cob, const float* __restrict__ cfb,
    float* __restrict__ x1, int M)
{
    constexpr int O = 32, TX = 8, MT = 128, ASTR = 132;
    __shared__ float As[16][ASTR];
    __shared__ float Bs[16 * O];
    int which = blockIdx.y;
    const float* A    = which ? S_cf : S_co;
    const float* B    = which ? cfW  : coW;
    const float* bias = which ? cfb  : cob;
    int Kdim = which ? 256 : 192;
    int ooff = which ? 32 : 0;
    int tid = threadIdx.x;
    int tx = tid % TX, ty = tid / TX;
    int m0 = blockIdx.x * MT;
    int ntiles = Kdim >> 4;
    float acc[4][4] = {};
    for (int t = 0; t < ntiles; ++t) {
        int k0 = t << 4;
        __syncthreads();
#pragma unroll
        for (int l = 0; l < 2; ++l) {
            int idx = tid + l * 256;
            int mm = idx >> 2, k4 = idx & 3;
            int gm = m0 + mm; if (gm >= M) gm = M - 1;
            float4 av = *reinterpret_cast<const float4*>(A + (size_t)gm * Kdim + k0 + k4 * 4);
            As[k4*4+0][mm] = av.x; As[k4*4+1][mm] = av.y;
            As[k4*4+2][mm] = av.z; As[k4*4+3][mm] = av.w;
        }
        if (tid < 128)
            *reinterpret_cast<float4*>(&Bs[tid*4]) =
                *reinterpret_cast<const float4*>(B + (size_t)k0 * O + tid * 4);
        __syncthreads();
#pragma unroll
        for (int kk = 0; kk < 16; ++kk) {
            float4 av = *reinterpret_cast<const float4*>(&As[kk][ty*4]);
            float4 bv = *reinterpret_cast<const float4*>(&Bs[kk*O + tx*4]);
            float aa[4] = {av.x, av.y, av.z, av.w};
            float bb[4] = {bv.x, bv.y, bv.z, bv.w};
#pragma unroll
            for (int i = 0; i < 4; ++i)
#pragma unroll
                for (int jj = 0; jj < 4; ++jj)
                    acc[i][jj] += aa[i] * bb[jj];
        }
    }
#pragma unroll
    for (int i = 0; i < 4; ++i) {
        int gm = m0 + ty*4 + i;
        if (gm < M)
#pragma unroll
            for (int jj = 0; jj < 4; ++jj)
                x1[(size_t)gm * 96 + ooff + tx*4 + jj] = acc[i][jj] + bias[tx*4 + jj];
    }
}

// ---- MFMA G-GEMM: G[j, n] = relu(feats[j,:]) . Bt[n,:]  (bf16 in/out) -------
template<int F>
__global__ __launch_bounds__(256) void gemmGm_kernel(
    const float* __restrict__ feats,            // [M,F] fp32
    const unsigned short* __restrict__ Bt,      // [NO,F] bf16 (n-major)
    unsigned short* __restrict__ G,             // [M,NO] bf16
    int M)
{
    constexpr int AST = F + 8;
    __shared__ unsigned short As[64 * AST];     // [m][k]
    __shared__ unsigned short Bs[64 * AST];     // [n][k]
    int tid = threadIdx.x, lane = tid & 63, wv = tid >> 6;
    int m0 = blockIdx.x * 64, no0 = blockIdx.y * 64;
    for (int i = tid; i < 64 * F / 4; i += 256) {
        int m = i / (F / 4), k4 = i % (F / 4);
        int gm = m0 + m; if (gm >= M) gm = M - 1;
        float4 av = *reinterpret_cast<const float4*>(feats + (size_t)gm * F + k4 * 4);
        uint2 o;
        o.x = bf16rne(fmaxf(av.x, 0.f)) | (bf16rne(fmaxf(av.y, 0.f)) << 16);
        o.y = bf16rne(fmaxf(av.z, 0.f)) | (bf16rne(fmaxf(av.w, 0.f)) << 16);
        *reinterpret_cast<uint2*>(As + m * AST + k4 * 4) = o;
    }
    for (int i = tid; i < 64 * F / 8; i += 256) {
        int n = i / (F / 8), k8 = i % (F / 8);
        *reinterpret_cast<uint4*>(Bs + n * AST + k8 * 8) =
            *reinterpret_cast<const uint4*>(Bt + (size_t)(no0 + n) * F + k8 * 8);
    }
    __syncthreads();
    int mr = lane & 15, quad = lane >> 4;
    f32x4 acc[4] = {{0.f,0.f,0.f,0.f},{0.f,0.f,0.f,0.f},
                    {0.f,0.f,0.f,0.f},{0.f,0.f,0.f,0.f}};
#pragma unroll
    for (int kc = 0; kc < F; kc += 32) {
        bf16x8 a = *reinterpret_cast<const bf16x8*>(As + (wv*16 + mr) * AST + kc + quad*8);
#pragma unroll
        for (int t = 0; t < 4; ++t) {
            bf16x8 b = *reinterpret_cast<const bf16x8*>(Bs + (t*16 + mr) * AST + kc + quad*8);
            acc[t] = __builtin_amdgcn_mfma_f32_16x16x32_bf16(a, b, acc[t], 0, 0, 0);
        }
    }
    // C layout: col = lane&15, row = quad*4 + reg
#pragma unroll
    for (int t = 0; t < 4; ++t) {
#pragma unroll
        for (int r = 0; r < 4; ++r) {
            int gm = m0 + wv*16 + quad*4 + r;
            if (gm < M)
                G[(size_t)gm * NO + no0 + t*16 + mr] = (unsigned short)bf16rne(acc[t][r]);
        }
    }
}

// ---- G-gather: 2 waves per query (even/odd k), 4 independent accumulators,
//      LDS combine; FUSEY=1 also computes Y = relu(x3)*W3p (2 queries/block) --
template<int FUSEY>
__global__ __launch_bounds__(256) void gatherG_kernel(
    const int* __restrict__ order,
    const int* __restrict__ cnt, const int* __restrict__ nidx,
    const int* __restrict__ ncell, const float* __restrict__ ncoef,
    const unsigned short* __restrict__ G,
    const float* __restrict__ cb, const float* __restrict__ db,
    const float* __restrict__ resid, float* __restrict__ out,
    const float* __restrict__ W3p, float* __restrict__ Y)
{
    __shared__ float part[2][2][64];   // [query][k-half][o]
    __shared__ float xs[2][64];
    __shared__ int qn[2];
    int lb = (blockIdx.x & 7) * (gridDim.x >> 3) + (blockIdx.x >> 3);
    int tid = threadIdx.x;
    int wv = tid >> 6, lane = tid & 63;
    int ql = wv >> 1;        // query-in-block (0/1)
    int half = wv & 1;       // k parity handled by this wave
    int w = lb * 2 + ql;
    bool valid = w < NQ;
    int n = valid ? order[w] : 0;
    int cn = valid ? cnt[n] : 0;
    int kk2 = 64 + lane;
    int cb1 = (lane < cn) ? ncell[n*K + lane] : 0;
    int j1  = (lane < cn) ? nidx [n*K + lane] : 0;
    int cb2 = (kk2 < cn) ? ncell[n*K + kk2] : 0;
    int j2  = (kk2 < cn) ? nidx [n*K + kk2] : 0;
    float a0 = 0.f, a1 = 0.f, a2 = 0.f, a3 = 0.f;
    const float* cfp = ncoef + (size_t)n * K * 8;
#pragma unroll 2
    for (int k = half; k < cn; k += 2) {
        int j    = (k < 64) ? __shfl(j1, k)  : __shfl(j2, k - 64);
        int cbse = (k < 64) ? __shfl(cb1, k) : __shfl(cb2, k - 64);
        float4 cA = *reinterpret_cast<const float4*>(cfp + k*8);      // c=0..3 (dx=0)
        float4 cB = *reinterpret_cast<const float4*>(cfp + k*8 + 4);  // c=4..7 (dx=1)
        const unsigned short* Gj = G + (size_t)j * NO + lane;
        // c = dx*4+dy*2+dz ; cell = cbse + dz*16 + dy*4 + dx
        a0 += cA.x * bf16f(Gj[(cbse     ) * 64]);
        a1 += cA.y * bf16f(Gj[(cbse + 16) * 64]);
        a2 += cA.z * bf16f(Gj[(cbse +  4) * 64]);
        a3 += cA.w * bf16f(Gj[(cbse + 20) * 64]);
        a0 += cB.x * bf16f(Gj[(cbse +  1) * 64]);
        a1 += cB.y * bf16f(Gj[(cbse + 17) * 64]);
        a2 += cB.z * bf16f(Gj[(cbse +  5) * 64]);
        a3 += cB.w * bf16f(Gj[(cbse + 21) * 64]);
    }
    part[ql][half][lane] = (a0 + a1) + (a2 + a3);
    __syncthreads();
    if (half == 0) {
        float acc = cb[lane] + db[lane] + part[ql][0][lane] + part[ql][1][lane];
        acc += bf16f(G[(size_t)n * NO + 64*64 + lane]);   // dense skip
        if (resid) acc += resid[(size_t)n * 64 + lane];
        if (!FUSEY) {
            if (valid) out[(size_t)n * 64 + lane] = acc;
        } else {
            xs[ql][lane] = valid ? fmaxf(acc, 0.f) : 0.f;
            if (lane == 0) qn[ql] = valid ? n : -1;
        }
    }
    if (FUSEY) {
        __syncthreads();
        // fused y3t: Y[n, t] = sum_f relu(x3[n,f]) * W3p[f,t]   (t < 195)
        for (int idx = tid; idx < 2 * 195; idx += 256) {
            int q = idx / 195, t = idx - q * 195;
            int nn = qn[q];
            if (nn >= 0) {
                float s = 0.f;
#pragma unroll 16
                for (int f = 0; f < 64; ++f) s += xs[q][f] * W3p[f*195 + t];
                Y[(size_t)nn * 195 + t] = s;
            }
        }
    }
}

// --- prep: Bt1/Bt2 (bf16 G-GEMM filters), W3p, ff, dense-0, grid counts ------
__global__ __launch_bounds__(256) void prep_kernel(
    const float* __restrict__ c1w, const float* __restrict__ d1w,
    const float* __restrict__ c2w, const float* __restrict__ d2w,
    const float* __restrict__ c3w, const float* __restrict__ d3w,
    const float* __restrict__ pos, const float* __restrict__ box,
    const float* __restrict__ vel,
    const float* __restrict__ d0w, const float* __restrict__ d0b,
    unsigned short* __restrict__ Bt1, unsigned short* __restrict__ Bt2,
    float* __restrict__ W3p, float* __restrict__ ff, float* __restrict__ x1,
    int* __restrict__ gcnt)
{
    int stride = gridDim.x * blockDim.x;
    int gid = blockIdx.x * blockDim.x + threadIdx.x;
    for (int i = gid; i < NQ + NB; i += stride) {   // grid occupancy counts
        const float* p = (i < NQ) ? pos + (size_t)i*3 : box + (size_t)(i-NQ)*3;
        atomicAdd(&gcnt[((i < NQ) ? 0 : NC) + cell_of(p[0], p[1], p[2])], 1);
    }
    for (int i = gid; i < NO * 96; i += stride) {   // Bt1[n,f]; n = c*64+o
        int n = i / 96, f = i % 96, c = n >> 6, o = n & 63;
        float v = (c < 64) ? c1w[((size_t)c*96 + f)*64 + o] : d1w[f*64 + o];
        Bt1[i] = (unsigned short)bf16rne(v);
    }
    for (int i = gid; i < NO * 64; i += stride) {
        int n = i / 64, f = i % 64, c = n >> 6, o = n & 63;
        float v = (c < 64) ? c2w[((size_t)c*64 + f)*64 + o] : d2w[f*64 + o];
        Bt2[i] = (unsigned short)bf16rne(v);
    }
    for (int i = gid; i < 64 * 195; i += stride) {   // W3p[f][c*3+o]
        int f = i / 195, r = i % 195, c = r / 3, o = r % 3;
        W3p[i] = (c < 64) ? c3w[(c*64 + f)*3 + o] : d3w[f*3 + o];
    }
    for (int i = gid; i < NQ; i += stride) {
        ff[i*4+0] = 1.f;
        ff[i*4+1] = vel[i*3+0];
        ff[i*4+2] = vel[i*3+1];
        ff[i*4+3] = vel[i*3+2];
    }
    for (int i = gid; i < NQ * 32; i += stride) {    // dense-0 skip -> x1[:,64:96]
        int n = i >> 5, o = i & 31;
        float acc = d0b[o] + d0w[o]
                  + vel[n*3+0] * d0w[32 + o]
                  + vel[n*3+1] * d0w[64 + o]
                  + vel[n*3+2] * d0w[96 + o];
        x1[n*96 + 64 + o] = acc;
    }
}

__global__ __launch_bounds__(256) void gather3_kernel(
    const int* __restrict__ order,
    const int* __restrict__ cnt, const int* __restrict__ nidx,
    const int* __restrict__ ncell, const float* __restrict__ ncoef,
    const float* __restrict__ Y,
    const float* __restrict__ cb3, const float* __restrict__ db3,
    float* __restrict__ out)
{
    int lb = (blockIdx.x & 7) * (gridDim.x >> 3) + (blockIdx.x >> 3);
    int gw = lb * 4 + ((int)threadIdx.x >> 6);
    int lane = threadIdx.x & 63;
    if (gw >= NQ) return;
    int n = order[gw];
    int cn = cnt[n];
    float a0 = 0.f, a1 = 0.f, a2 = 0.f;
#pragma unroll
    for (int seg = 0; seg < 2; ++seg) {
        int kidx = seg * 64 + lane;
        if (kidx < cn) {
            int j  = nidx [n*K + kidx];
            int cb = ncell[n*K + kidx];
            const float* cf = ncoef + (size_t)(n*K + kidx) * 8;
            const float* Yj = Y + (size_t)j * 195;
#pragma unroll
            for (int c = 0; c < 8; ++c) {
                int cell = cb + (c & 1)*16 + ((c >> 1) & 1)*4 + (c >> 2);
                float wgt = cf[c];
                const float* Tp = Yj + cell*3;
                a0 += wgt * Tp[0];
                a1 += wgt * Tp[1];
                a2 += wgt * Tp[2];
            }
        }
    }
#pragma unroll
    for (int s = 32; s > 0; s >>= 1) {
        a0 += __shfl_down(a0, s);
        a1 += __shfl_down(a1, s);
        a2 += __shfl_down(a2, s);
    }
    if (lane == 0) {
        const float* Yn = Y + (size_t)n * 195 + 192;   // dense skip (c=64)
        out[n*3+0] = (a0 + Yn[0] + cb3[0] + db3[0]) * (1.f/128.f);
        out[n*3+1] = (a1 + Yn[1] + cb3[1] + db3[1]) * (1.f/128.f);
        out[n*3+2] = (a2 + Yn[2] + cb3[2] + db3[2]) * (1.f/128.f);
    }
}

} // namespace

extern "C" void kernel_launch(void* const* d_in, const int* in_sizes, int n_in,
                              void* d_out, int out_size, void* d_ws, size_t ws_size,
                              hipStream_t stream)
{
    const float* pos       = (const float*)d_in[0];
    const float* vel       = (const float*)d_in[1];
    const float* box       = (const float*)d_in[2];
    const float* box_feats = (const float*)d_in[3];
    const float* cf_w = (const float*)d_in[4];  const float* cf_b = (const float*)d_in[5];
    const float* co_w = (const float*)d_in[6];  const float* co_b = (const float*)d_in[7];
    const float* d0_w = (const float*)d_in[8];  const float* d0_b = (const float*)d_in[9];
    const float* c1_w = (const float*)d_in[10]; const float* c1_b = (const float*)d_in[11];
    const float* d1_w = (const float*)d_in[12]; const float* d1_b = (const float*)d_in[13];
    const float* c2_w = (const float*)d_in[14]; const float* c2_b = (const float*)d_in[15];
    const float* d2_w = (const float*)d_in[16]; const float* d2_b = (const float*)d_in[17];
    const float* c3_w = (const float*)d_in[18]; const float* c3_b = (const float*)d_in[19];
    const float* d3_w = (const float*)d_in[20]; const float* d3_b = (const float*)d_in[21];

    char* wsb = (char*)d_ws;
    size_t off = 0;
    auto alloc = [&](size_t bytes) {
        void* p = wsb + off;
        off = (off + bytes + 255) & ~(size_t)255;
        return p;
    };
    // Big region time-shared: {f_d2,b_d2} during nn -> {S_cf,S_co} (layer 0)
    // -> bf16 G rows for layers 1/2.
    char*  Graw = (char*)alloc((size_t)NQ * NO * 2 + 4096);   // 50 MB
    unsigned short* G = (unsigned short*)Graw;
    float* f_d2 = (float*)Graw;
    float* b_d2 = (float*)Graw + (size_t)NQ * K;
    float* S_cf = (float*)Graw;                      // [NQ,256] fp32
    float* S_co = (float*)Graw + (size_t)NQ * 256;   // [NQ,192] fp32
    int*   f_cnt  = (int*)  alloc((size_t)NQ * 4);
    int*   f_idx  = (int*)  alloc((size_t)NQ * K * 4);
    int*   f_cell = (int*)  alloc((size_t)NQ * K * 4);
    float* f_coef = (float*)alloc((size_t)NQ * K * 8 * 4);
    int*   b_cnt  = (int*)  alloc((size_t)NQ * 4);
    int*   b_idx  = (int*)  alloc((size_t)NQ * K * 4);
    int*   b_cell = (int*)  alloc((size_t)NQ * K * 4);
    float* b_coef = (float*)alloc((size_t)NQ * K * 8 * 4);
    float* ff     = (float*)alloc((size_t)NQ * 4 * 4);
    float* x1     = (float*)alloc((size_t)NQ * 96 * 4);
    float* x2     = (float*)alloc((size_t)NQ * 64 * 4);
    unsigned short* Bt1 = (unsigned short*)alloc((size_t)NO * 96 * 2);  // 0.8 MB
    unsigned short* Bt2 = (unsigned short*)alloc((size_t)NO * 64 * 2);  // 0.5 MB
    float* W3p    = (float*)alloc((size_t)64 * 195 * 4);
    float* Y      = (float*)alloc((size_t)NQ * 195 * 4);
    // grid structures
    int*   gcnt   = (int*)  alloc((size_t)2 * NC * 4);
    int*   gs_f   = (int*)  alloc((size_t)(NC + 1) * 4);
    int*   gs_b   = (int*)  alloc((size_t)(NC + 1) * 4);
    int*   cur_f  = (int*)  alloc((size_t)NC * 4);
    int*   cur_b  = (int*)  alloc((size_t)NC * 4);
    float* spf    = (float*)alloc((size_t)NQ * 3 * 4);
    int*   sif    = (int*)  alloc((size_t)NQ * 4);
    float* spb    = (float*)alloc((size_t)NB * 3 * 4);
    int*   sib    = (int*)  alloc((size_t)NB * 4);

    dim3 b256(256);
    hipMemsetAsync(gcnt, 0, (size_t)2 * NC * 4, stream);
    prep_kernel<<<512, b256, 0, stream>>>(c1_w, d1_w, c2_w, d2_w, c3_w, d3_w,
                                          pos, box, vel, d0_w, d0_b,
                                          Bt1, Bt2, W3p, ff, x1, gcnt);
    scan_kernel<<<1, 512, 0, stream>>>(gcnt, gs_f, gs_b, cur_f, cur_b);
    scatter_pts_kernel<<<(NQ + NB + 255)/256, b256, 0, stream>>>(
        pos, box, cur_f, cur_b, spf, sif, spb, sib);
    nn2gc_kernel<<<(2*NQ*64 + 255)/256, b256, 0, stream>>>(
        pos, spf, sif, gs_f, spb, sib, gs_b,
        f_cnt, f_idx, f_d2, f_cell, f_coef,
        b_cnt, b_idx, b_d2, b_cell, b_coef);
    // ---- layer 0: merged scatters + dual GEMM (bias fused) ----
    scatter0_kernel<<<2*((NQ+3)/4), b256, 0, stream>>>(
        ff, f_cnt, f_idx, f_cell, f_coef,
        box_feats, b_cnt, b_idx, b_cell, b_coef, S_cf, S_co);
    gemm0_kernel<<<dim3((NQ+127)/128, 2), b256, 0, stream>>>(
        S_co, S_cf, co_w, cf_w, co_b, cf_b, x1, NQ);
    // ---- layer 1: G1 = relu(x1) x [c1;d1] (MFMA) ; x2 = gather(G1) + biases --
    gemmGm_kernel<96><<<dim3((NQ+63)/64, NO/64), b256, 0, stream>>>(x1, Bt1, G, NQ);
    gatherG_kernel<0><<<NG2, b256, 0, stream>>>(sif, f_cnt, f_idx, f_cell, f_coef,
        G, c1_b, d1_b, nullptr, x2, nullptr, nullptr);
    // ---- layer 2: G2 = relu(x2) x [c2;d2] (MFMA) ;
    //      fused: x3 = gather + biases + x2 ; Y = relu(x3) * [c3;d3] ----
    gemmGm_kernel<64><<<dim3((NQ+63)/64, NO/64), b256, 0, stream>>>(x2, Bt2, G, NQ);
    gatherG_kernel<1><<<NG2, b256, 0, stream>>>(sif, f_cnt, f_idx, f_cell, f_coef,
        G, c2_b, d2_b, x2, nullptr, W3p, Y);
    // ---- layer 3 gather (O=3) ----
    gather3_kernel<<<NBLK8, b256, 0, stream>>>(sif, f_cnt, f_idx, f_cell, f_coef,
        Y, c3_b, d3_b, (float*)d_out);

    (void)in_sizes; (void)n_in; (void)out_size; (void)ws_size;
    (void)f_d2; (void)b_d2;
}

// Round 13
// 292.258 us; speedup vs baseline: 1.0683x; 1.0683x over previous
//
#include <hip/hip_runtime.h>
#include <math.h>

namespace {

constexpr int NQ  = 6000;   // fluid particles (queries)
constexpr int NB  = 3000;   // box particles
constexpr int K   = 80;     // neighbor cap
constexpr float RAD = 0.1125f;
constexpr float R2  = RAD * RAD;
constexpr float EPSF = 1e-12f;

constexpr int GS  = 8;           // grid dim (cell 0.125 >= RADIUS)
constexpr int NC  = GS*GS*GS;    // 512 cells
constexpr int NO  = 65 * 64;     // G row: 64 cells + 1 dense-skip col, O=64
constexpr int NBLK = (NQ + 3) / 4;            // gather blocks (4 queries each)
constexpr int NBLK8 = ((NBLK + 7) / 8) * 8;   // padded for XCD swizzle

typedef __attribute__((ext_vector_type(8))) short bf16x8;
typedef __attribute__((ext_vector_type(4))) float f32x4;

__device__ __forceinline__ float sgn(float x) {
    return (x > 0.f) ? 1.f : ((x < 0.f) ? -1.f : 0.f);
}

__device__ __forceinline__ unsigned int bf16rne(float f) {
    unsigned int u = __float_as_uint(f);
    return (u + 0x7fffu + ((u >> 16) & 1u)) >> 16;   // round-to-nearest-even
}
__device__ __forceinline__ float bf16f(unsigned short u) {
    return __uint_as_float(((unsigned int)u) << 16);
}
__device__ __forceinline__ int cell_of(float x, float y, float z) {
    int cx = min(max((int)(x * (float)GS), 0), GS-1);
    int cy = min(max((int)(y * (float)GS), 0), GS-1);
    int cz = min(max((int)(z * (float)GS), 0), GS-1);
    return (cz*GS + cy)*GS + cx;
}

// ball->cube + trilinear coefs from raw delta (ddx = pj - q), store at slot
__device__ void coef_store(float ddx, float ddy, float ddz, int slot,
                           int* __restrict__ cells, float* __restrict__ coefs)
{
    float rx = ddx / RAD, ry = ddy / RAD, rz = ddz / RAD;
    float r2 = rx*rx + ry*ry + rz*rz;
    float w1 = 1.f - r2;
    float win = (w1 > 0.f) ? w1*w1*w1 : 0.f;   // clip((1-r2)^3, 0, 1)
    float norm = sqrtf(r2);
    float rxy2 = rx*rx + ry*ry;
    float xc, yc, zc;
    if (r2 < 1e-12f) {
        xc = yc = zc = 0.f;
    } else if (1.25f * rz * rz > rxy2) {
        float s = sqrtf(3.0f * norm / (norm + fabsf(rz) + EPSF));
        xc = s * rx; yc = s * ry; zc = sgn(rz) * norm;
    } else {
        float s = norm / sqrtf(rxy2 + EPSF);
        xc = s * rx; yc = s * ry; zc = 1.5f * rz * s;
    }
    float rxy = sqrtf(xc*xc + yc*yc);
    const float FP = (float)(4.0 / M_PI);
    float u, v;
    if (rxy < EPSF) {
        u = 0.f; v = 0.f;
    } else if (fabsf(xc) >= fabsf(yc)) {
        float sx = (fabsf(xc) < EPSF) ? EPSF : xc;
        u = sgn(xc) * rxy;
        v = u * FP * atanf(yc / sx);
    } else {
        float sy = (fabsf(yc) < EPSF) ? EPSF : yc;
        v = sgn(yc) * rxy;
        u = v * FP * atanf(xc / sy);
    }
    float gx = fminf(fmaxf((u  + 1.f) * 0.5f * 3.f, 0.f), 3.f);
    float gy = fminf(fmaxf((v  + 1.f) * 0.5f * 3.f, 0.f), 3.f);
    float gz = fminf(fmaxf((zc + 1.f) * 0.5f * 3.f, 0.f), 3.f);
    int ix = min((int)floorf(gx), 2);
    int iy = min((int)floorf(gy), 2);
    int iz = min((int)floorf(gz), 2);
    float tx = gx - (float)ix, ty = gy - (float)iy, tz = gz - (float)iz;
    cells[slot] = iz*16 + iy*4 + ix;
    float wx[2] = {1.f - tx, tx}, wy[2] = {1.f - ty, ty}, wz[2] = {1.f - tz, tz};
    float* cf = coefs + (size_t)slot * 8;
#pragma unroll
    for (int c = 0; c < 8; ++c)   // c = dx*4 + dy*2 + dz (python loop order)
        cf[c] = wx[c >> 2] * wy[(c >> 1) & 1] * wz[c & 1] * win;
}

// ---------------- grid build -------------------------------------------------
__global__ __launch_bounds__(512) void scan_kernel(
    const int* __restrict__ gcnt,
    int* __restrict__ gs_f, int* __restrict__ gs_b,
    int* __restrict__ cur_f, int* __restrict__ cur_b)
{
    __shared__ int tmp[NC];
    int tid = threadIdx.x;
#pragma unroll
    for (int a = 0; a < 2; ++a) {
        int cntv = gcnt[a*NC + tid];
        tmp[tid] = cntv;
        __syncthreads();
        for (int off = 1; off < NC; off <<= 1) {
            int v = (tid >= off) ? tmp[tid - off] : 0;
            __syncthreads();
            tmp[tid] += v;
            __syncthreads();
        }
        int* gsd = a ? gs_b : gs_f;
        int* cur = a ? cur_b : cur_f;
        int excl = tmp[tid] - cntv;
        gsd[tid] = excl;
        cur[tid] = excl;
        if (tid == NC - 1) gsd[NC] = tmp[tid];
        __syncthreads();
    }
}

__global__ __launch_bounds__(256) void scatter_pts_kernel(
    const float* __restrict__ pos, const float* __restrict__ box,
    int* __restrict__ cur_f, int* __restrict__ cur_b,
    float* __restrict__ spf, int* __restrict__ sif,
    float* __restrict__ spb, int* __restrict__ sib)
{
    int t = blockIdx.x * blockDim.x + threadIdx.x;
    if (t < NQ) {
        float x = pos[t*3], y = pos[t*3+1], z = pos[t*3+2];
        int dst = atomicAdd(&cur_f[cell_of(x,y,z)], 1);
        spf[dst*3] = x; spf[dst*3+1] = y; spf[dst*3+2] = z;
        sif[dst] = t;
    } else if (t < NQ + NB) {
        int b = t - NQ;
        float x = box[b*3], y = box[b*3+1], z = box[b*3+2];
        int dst = atomicAdd(&cur_b[cell_of(x,y,z)], 1);
        spb[dst*3] = x; spb[dst*3+1] = y; spb[dst*3+2] = z;
        sib[dst] = b;
    }
}

// -------- fused neighbor search + coef compute (one wave per query) ----------
__global__ __launch_bounds__(256) void nn2gc_kernel(
    const float* __restrict__ pos,
    const float* __restrict__ spf, const int* __restrict__ sif, const int* __restrict__ gsf,
    const float* __restrict__ spb, const int* __restrict__ sib, const int* __restrict__ gsb,
    int* __restrict__ f_cnt, int* __restrict__ f_idx, float* __restrict__ f_d2,
    int* __restrict__ f_cell, float* __restrict__ f_coef,
    int* __restrict__ b_cnt, int* __restrict__ b_idx, float* __restrict__ b_d2,
    int* __restrict__ b_cell, float* __restrict__ b_coef)
{
    int gw = (blockIdx.x * blockDim.x + threadIdx.x) >> 6;
    int lane = threadIdx.x & 63;
    if (gw >= 2 * NQ) return;
    bool isF = gw < NQ;
    int wid = isF ? gw : gw - NQ;
    const float* sp = isF ? spf : spb;
    const int*   si = isF ? sif : sib;
    const int*   gs = isF ? gsf : gsb;
    int*   cnt   = isF ? f_cnt  : b_cnt;
    int*   idxs  = isF ? f_idx  : b_idx;
    float* d2s   = isF ? f_d2   : b_d2;
    int*   cells = isF ? f_cell : b_cell;
    float* coefs = isF ? f_coef : b_coef;
    float qx = pos[wid*3+0], qy = pos[wid*3+1], qz = pos[wid*3+2];
    int cx = min(max((int)(qx * (float)GS), 0), GS-1);
    int cy = min(max((int)(qy * (float)GS), 0), GS-1);
    int cz = min(max((int)(qz * (float)GS), 0), GS-1);
    int x0 = max(cx-1, 0), x1 = min(cx+1, GS-1);
    int base = wid * K;
    int c = 0;
    for (int dz = -1; dz <= 1; ++dz) {
        int z = cz + dz; if ((unsigned)z >= (unsigned)GS) continue;
        for (int dy = -1; dy <= 1; ++dy) {
            int y = cy + dy; if ((unsigned)y >= (unsigned)GS) continue;
            int row = (z*GS + y)*GS;
            int s0 = gs[row + x0], s1 = gs[row + x1 + 1];
            for (int j0 = s0; j0 < s1; j0 += 64) {
                int ii = j0 + lane;
                float d2 = 1e30f; int oj = 0;
                float ddx = 0.f, ddy = 0.f, ddz = 0.f;
                if (ii < s1) {
                    oj = si[ii];
                    ddx = sp[ii*3+0]-qx; ddy = sp[ii*3+1]-qy; ddz = sp[ii*3+2]-qz;
                    d2 = ddx*ddx + ddy*ddy + ddz*ddz;
                    if (isF && oj == wid) d2 = 1e30f;
                }
                bool hit = d2 <= R2;
                unsigned long long m = __ballot(hit);
                int pc = __popcll(m);
                if (pc == 0) continue;
                if (c + pc <= K) {
                    if (hit) {
                        int p = c + __popcll(m & ((1ull << lane) - 1ull));
                        idxs[base + p] = oj;
                        d2s [base + p] = d2;
                        coef_store(ddx, ddy, ddz, base + p, cells, coefs);
                    }
                    c += pc;
                } else {
                    // rare overflow: keep the K nearest (top_k semantics)
                    while (m) {
                        int l = __ffsll((unsigned long long)m) - 1;
                        m &= m - 1ull;
                        float dd = __shfl(d2, l);
                        int jv = __shfl(oj, l);
                        float ax = __shfl(ddx, l), ay = __shfl(ddy, l), az = __shfl(ddz, l);
                        int slot = -1;
                        if (c < K) { slot = c; c++; }
                        else {
                            float mx = -1.f; int am = 0;
                            for (int s = 0; s < K; ++s) {
                                float v = d2s[base + s];
                                if (v > mx) { mx = v; am = s; }
                            }
                            if (dd < mx) slot = am;
                        }
                        if (slot >= 0 && lane == 0) {
                            idxs[base + slot] = jv;
                            d2s [base + slot] = dd;
                            coef_store(ax, ay, az, base + slot, cells, coefs);
                        }
                    }
                }
            }
        }
    }
    if (lane == 0) cnt[wid] = c;
}

// ------- small scatter (F in {3,4}): one WAVE per point, lane=(corner,feat) --
template<int F>
__device__ void scatter_small_dev(
    const float* __restrict__ feats,
    const int* __restrict__ cnt, const int* __restrict__ nidx,
    const int* __restrict__ ncell, const float* __restrict__ ncoef,
    float* __restrict__ Sg, int blk)
{
    __shared__ __align__(16) float S4[4][64 * F];
    int tid = threadIdx.x, lane = tid & 63, w = tid >> 6;
    int n = blk * 4 + w;
    if (n >= NQ) return;
    float* Sw = S4[w];
    for (int i = lane; i < 64 * F; i += 64) Sw[i] = 0.f;
    int cn = cnt[n];
    int kk2 = 64 + lane;
    int cb1 = (lane < cn) ? ncell[n*K + lane] : 0;
    int j1  = (lane < cn) ? nidx [n*K + lane] : 0;
    int cb2 = (kk2 < cn) ? ncell[n*K + kk2] : 0;
    int j2  = (kk2 < cn) ? nidx [n*K + kk2] : 0;
    int c = lane & 7, f = lane >> 3;
    bool fok = f < F;
    const float* coefG = ncoef + (size_t)n * K * 8;

    float wgt = 0.f, v = 0.f; int cb = 0;
    if (cn > 0) {
        int j = __shfl(j1, 0); cb = __shfl(cb1, 0);
        if (fok) { wgt = coefG[c]; v = feats[(size_t)j * F + f]; }
    }
    for (int kk = 0; kk < cn; ++kk) {
        float wn = 0.f, vn = 0.f; int cbn = 0;
        int k1n = kk + 1;
        if (k1n < cn) {
            int jn = (k1n < 64) ? __shfl(j1, k1n) : __shfl(j2, k1n - 64);
            cbn    = (k1n < 64) ? __shfl(cb1, k1n) : __shfl(cb2, k1n - 64);
            if (fok) { wn = coefG[k1n*8 + c]; vn = feats[(size_t)jn * F + f]; }
        }
        if (fok) {
            int cell = cb + (c & 1)*16 + ((c >> 1) & 1)*4 + (c >> 2);
            Sw[cell*F + f] += wgt * v;
        }
        wgt = wn; v = vn; cb = cbn;
    }
    float* row = Sg + (size_t)n * (64 * F);
    for (int i = lane; i < 16 * F; i += 64)
        ((float4*)row)[i] = ((const float4*)Sw)[i];
}

// merged layer-0 scatters: blocks [0,FB) = fluid F=4, [FB,2FB) = box F=3
__global__ __launch_bounds__(256) void scatter0_kernel(
    const float* __restrict__ ff,
    const int* __restrict__ f_cnt, const int* __restrict__ f_idx,
    const int* __restrict__ f_cell, const float* __restrict__ f_coef,
    const float* __restrict__ bfeat,
    const int* __restrict__ b_cnt, const int* __restrict__ b_idx,
    const int* __restrict__ b_cell, const float* __restrict__ b_coef,
    float* __restrict__ S_cf, float* __restrict__ S_co)
{
    constexpr int FB = (NQ + 3) / 4;
    if (blockIdx.x < FB)
        scatter_small_dev<4>(ff, f_cnt, f_idx, f_cell, f_coef, S_cf, blockIdx.x);
    else
        scatter_small_dev<3>(bfeat, b_cnt, b_idx, b_cell, b_coef, S_co, blockIdx.x - FB);
}

// ---- layer-0 dual GEMM, full-K per block, bias fused, writes x1 directly ----
__global__ __launch_bounds__(256) void gemm0_kernel(
    const float* __restrict__ S_co, const float* __restrict__ S_cf,
    const float* __restrict__ coW, const float* __restrict__ cfW,
    const float* __restrict__ cob, const float* __restrict__ cfb,
    float* __restrict__ x1, int M)
{
    constexpr int O = 32, TX = 8, MT = 128, ASTR = 132;
    __shared__ float As[16][ASTR];
    __shared__ float Bs[16 * O];
    int which = blockIdx.y;
    const float* A    = which ? S_cf : S_co;
    const float* B    = which ? cfW  : coW;
    const float* bias = which ? cfb  : cob;
    int Kdim = which ? 256 : 192;
    int ooff = which ? 32 : 0;
    int tid = threadIdx.x;
    int tx = tid % TX, ty = tid / TX;
    int m0 = blockIdx.x * MT;
    int ntiles = Kdim >> 4;
    float acc[4][4] = {};
    for (int t = 0; t < ntiles; ++t) {
        int k0 = t << 4;
        __syncthreads();
#pragma unroll
        for (int l = 0; l < 2; ++l) {
            int idx = tid + l * 256;
            int mm = idx >> 2, k4 = idx & 3;
            int gm = m0 + mm; if (gm >= M) gm = M - 1;
            float4 av = *reinterpret_cast<const float4*>(A + (size_t)gm * Kdim + k0 + k4 * 4);
            As[k4*4+0][mm] = av.x; As[k4*4+1][mm] = av.y;
            As[k4*4+2][mm] = av.z; As[k4*4+3][mm] = av.w;
        }
        if (tid < 128)
            *reinterpret_cast<float4*>(&Bs[tid*4]) =
                *reinterpret_cast<const float4*>(B + (size_t)k0 * O + tid * 4);
        __syncthreads();
#pragma unroll
        for (int kk = 0; kk < 16; ++kk) {
            float4 av = *reinterpret_cast<const float4*>(&As[kk][ty*4]);
            float4 bv = *reinterpret_cast<const float4*>(&Bs[kk*O + tx*4]);
            float aa[4] = {av.x, av.y, av.z, av.w};
            float bb[4] = {bv.x, bv.y, bv.z, bv.w};
#pragma unroll
            for (int i = 0; i < 4; ++i)
#pragma unroll
                for (int jj = 0; jj < 4; ++jj)
                    acc[i][jj] += aa[i] * bb[jj];
        }
    }
#pragma unroll
    for (int i = 0; i < 4; ++i) {
        int gm = m0 + ty*4 + i;
        if (gm < M)
#pragma unroll
            for (int jj = 0; jj < 4; ++jj)
                x1[(size_t)gm * 96 + ooff + tx*4 + jj] = acc[i][jj] + bias[tx*4 + jj];
    }
}

// ---- MFMA G-GEMM: G[j, n] = relu(feats[j,:]) . Bt[n,:]  (bf16 in/out) -------
template<int F>
__global__ __launch_bounds__(256) void gemmGm_kernel(
    const float* __restrict__ feats,            // [M,F] fp32
    const unsigned short* __restrict__ Bt,      // [NO,F] bf16 (n-major)
    unsigned short* __restrict__ G,             // [M,NO] bf16
    int M)
{
    constexpr int AST = F + 8;
    __shared__ unsigned short As[64 * AST];     // [m][k]
    __shared__ unsigned short Bs[64 * AST];     // [n][k]
    int tid = threadIdx.x, lane = tid & 63, wv = tid >> 6;
    int m0 = blockIdx.x * 64, no0 = blockIdx.y * 64;
    for (int i = tid; i < 64 * F / 4; i += 256) {
        int m = i / (F / 4), k4 = i % (F / 4);
        int gm = m0 + m; if (gm >= M) gm = M - 1;
        float4 av = *reinterpret_cast<const float4*>(feats + (size_t)gm * F + k4 * 4);
        uint2 o;
        o.x = bf16rne(fmaxf(av.x, 0.f)) | (bf16rne(fmaxf(av.y, 0.f)) << 16);
        o.y = bf16rne(fmaxf(av.z, 0.f)) | (bf16rne(fmaxf(av.w, 0.f)) << 16);
        *reinterpret_cast<uint2*>(As + m * AST + k4 * 4) = o;
    }
    for (int i = tid; i < 64 * F / 8; i += 256) {
        int n = i / (F / 8), k8 = i % (F / 8);
        *reinterpret_cast<uint4*>(Bs + n * AST + k8 * 8) =
            *reinterpret_cast<const uint4*>(Bt + (size_t)(no0 + n) * F + k8 * 8);
    }
    __syncthreads();
    int mr = lane & 15, quad = lane >> 4;
    f32x4 acc[4] = {{0.f,0.f,0.f,0.f},{0.f,0.f,0.f,0.f},
                    {0.f,0.f,0.f,0.f},{0.f,0.f,0.f,0.f}};
#pragma unroll
    for (int kc = 0; kc < F; kc += 32) {
        bf16x8 a = *reinterpret_cast<const bf16x8*>(As + (wv*16 + mr) * AST + kc + quad*8);
#pragma unroll
        for (int t = 0; t < 4; ++t) {
            bf16x8 b = *reinterpret_cast<const bf16x8*>(Bs + (t*16 + mr) * AST + kc + quad*8);
            acc[t] = __builtin_amdgcn_mfma_f32_16x16x32_bf16(a, b, acc[t], 0, 0, 0);
        }
    }
    // C layout: col = lane&15, row = quad*4 + reg
#pragma unroll
    for (int t = 0; t < 4; ++t) {
#pragma unroll
        for (int r = 0; r < 4; ++r) {
            int gm = m0 + wv*16 + quad*4 + r;
            if (gm < M)
                G[(size_t)gm * NO + no0 + t*16 + mr] = (unsigned short)bf16rne(acc[t][r]);
        }
    }
}

// ---- G-gather: 1 wave/query, coefs staged in LDS (off the vmcnt chain),
//      4 independent accumulators, split k-loop; FUSEY=1 fuses Y = relu(x3)*W3p
template<int FUSEY>
__global__ __launch_bounds__(256) void gatherG_kernel(
    const int* __restrict__ order,
    const int* __restrict__ cnt, const int* __restrict__ nidx,
    const int* __restrict__ ncell, const float* __restrict__ ncoef,
    const unsigned short* __restrict__ G,
    const float* __restrict__ cb, const float* __restrict__ db,
    const float* __restrict__ resid, float* __restrict__ out,
    const float* __restrict__ W3p, float* __restrict__ Y)
{
    __shared__ __align__(16) float coefL[4][K * 8];   // 10 KB
    __shared__ float xs[4][64];
    __shared__ int qn[4];
    int lb = (blockIdx.x & 7) * (gridDim.x >> 3) + (blockIdx.x >> 3);
    int tid = threadIdx.x;
    int wv = tid >> 6, lane = tid & 63;
    int w = lb * 4 + wv;
    bool valid = w < NQ;
    if (!FUSEY && !valid) return;
    int n = valid ? order[w] : 0;
    int cn = valid ? cnt[n] : 0;
    // stage this query's coefs into LDS (wave-local; no barrier needed)
    {
        const float4* src = (const float4*)(ncoef + (size_t)n * K * 8);
        float4* dst = (float4*)coefL[wv];
        for (int i = lane; i < cn * 2; i += 64) dst[i] = src[i];
    }
    int kk2 = 64 + lane;
    int cb1 = (lane < cn) ? ncell[n*K + lane] : 0;
    int j1  = (lane < cn) ? nidx [n*K + lane] : 0;
    int cb2 = (kk2 < cn) ? ncell[n*K + kk2] : 0;
    int j2  = (kk2 < cn) ? nidx [n*K + kk2] : 0;
    float a0 = 0.f, a1 = 0.f, a2 = 0.f, a3 = 0.f;
    const float* cwv = coefL[wv];
    int c1e = min(cn, 64);
#pragma unroll 4
    for (int k = 0; k < c1e; ++k) {
        int j    = __shfl(j1, k);
        int cbse = __shfl(cb1, k);
        float4 cA = *reinterpret_cast<const float4*>(cwv + k*8);      // c=0..3 (dx=0)
        float4 cB = *reinterpret_cast<const float4*>(cwv + k*8 + 4);  // c=4..7 (dx=1)
        const unsigned short* Gj = G + (size_t)j * NO + lane;
        // c = dx*4+dy*2+dz ; cell = cbse + dz*16 + dy*4 + dx
        a0 += cA.x * bf16f(Gj[(cbse     ) * 64]);
        a1 += cA.y * bf16f(Gj[(cbse + 16) * 64]);
        a2 += cA.z * bf16f(Gj[(cbse +  4) * 64]);
        a3 += cA.w * bf16f(Gj[(cbse + 20) * 64]);
        a0 += cB.x * bf16f(Gj[(cbse +  1) * 64]);
        a1 += cB.y * bf16f(Gj[(cbse + 17) * 64]);
        a2 += cB.z * bf16f(Gj[(cbse +  5) * 64]);
        a3 += cB.w * bf16f(Gj[(cbse + 21) * 64]);
    }
    for (int k = 64; k < cn; ++k) {        // rarely taken (mean cn ~36)
        int j    = __shfl(j2, k - 64);
        int cbse = __shfl(cb2, k - 64);
        float4 cA = *reinterpret_cast<const float4*>(cwv + k*8);
        float4 cB = *reinterpret_cast<const float4*>(cwv + k*8 + 4);
        const unsigned short* Gj = G + (size_t)j * NO + lane;
        a0 += cA.x * bf16f(Gj[(cbse     ) * 64]);
        a1 += cA.y * bf16f(Gj[(cbse + 16) * 64]);
        a2 += cA.z * bf16f(Gj[(cbse +  4) * 64]);
        a3 += cA.w * bf16f(Gj[(cbse + 20) * 64]);
        a0 += cB.x * bf16f(Gj[(cbse +  1) * 64]);
        a1 += cB.y * bf16f(Gj[(cbse + 17) * 64]);
        a2 += cB.z * bf16f(Gj[(cbse +  5) * 64]);
        a3 += cB.w * bf16f(Gj[(cbse + 21) * 64]);
    }
    float acc = cb[lane] + db[lane] + ((a0 + a1) + (a2 + a3));
    acc += bf16f(G[(size_t)n * NO + 64*64 + lane]);   // dense skip
    if (resid) acc += resid[(size_t)n * 64 + lane];
    if (!FUSEY) {
        out[(size_t)n * 64 + lane] = acc;
    } else {
        // fused y3t: Y[n, t] = sum_f relu(x3[n,f]) * W3p[f,t]   (t < 195)
        xs[wv][lane] = valid ? fmaxf(acc, 0.f) : 0.f;
        if (lane == 0) qn[wv] = valid ? n : -1;
        __syncthreads();
        for (int idx = tid; idx < 4 * 195; idx += 256) {
            int q = idx / 195, t = idx - q * 195;
            int nn = qn[q];
            if (nn >= 0) {
                float s = 0.f;
#pragma unroll 16
                for (int f = 0; f < 64; ++f) s += xs[q][f] * W3p[f*195 + t];
                Y[(size_t)nn * 195 + t] = s;
            }
        }
    }
}

// --- prep: Bt1/Bt2 (bf16 G-GEMM filters), W3p, ff, dense-0, grid counts ------
__global__ __launch_bounds__(256) void prep_kernel(
    const float* __restrict__ c1w, const float* __restrict__ d1w,
    const float* __restrict__ c2w, const float* __restrict__ d2w,
    const float* __restrict__ c3w, const float* __restrict__ d3w,
    const float* __restrict__ pos, const float* __restrict__ box,
    const float* __restrict__ vel,
    const float* __restrict__ d0w, const float* __restrict__ d0b,
    unsigned short* __restrict__ Bt1, unsigned short* __restrict__ Bt2,
    float* __restrict__ W3p, float* __restrict__ ff, float* __restrict__ x1,
    int* __restrict__ gcnt)
{
    int stride = gridDim.x * blockDim.x;
    int gid = blockIdx.x * blockDim.x + threadIdx.x;
    for (int i = gid; i < NQ + NB; i += stride) {   // grid occupancy counts
        const float* p = (i < NQ) ? pos + (size_t)i*3 : box + (size_t)(i-NQ)*3;
        atomicAdd(&gcnt[((i < NQ) ? 0 : NC) + cell_of(p[0], p[1], p[2])], 1);
    }
    for (int i = gid; i < NO * 96; i += stride) {   // Bt1[n,f]; n = c*64+o
        int n = i / 96, f = i % 96, c = n >> 6, o = n & 63;
        float v = (c < 64) ? c1w[((size_t)c*96 + f)*64 + o] : d1w[f*64 + o];
        Bt1[i] = (unsigned short)bf16rne(v);
    }
    for (int i = gid; i < NO * 64; i += stride) {
        int n = i / 64, f = i % 64, c = n >> 6, o = n & 63;
        float v = (c < 64) ? c2w[((size_t)c*64 + f)*64 + o] : d2w[f*64 + o];
        Bt2[i] = (unsigned short)bf16rne(v);
    }
    for (int i = gid; i < 64 * 195; i += stride) {   // W3p[f][c*3+o]
        int f = i / 195, r = i % 195, c = r / 3, o = r % 3;
        W3p[i] = (c < 64) ? c3w[(c*64 + f)*3 + o] : d3w[f*3 + o];
    }
    for (int i = gid; i < NQ; i += stride) {
        ff[i*4+0] = 1.f;
        ff[i*4+1] = vel[i*3+0];
        ff[i*4+2] = vel[i*3+1];
        ff[i*4+3] = vel[i*3+2];
    }
    for (int i = gid; i < NQ * 32; i += stride) {    // dense-0 skip -> x1[:,64:96]
        int n = i >> 5, o = i & 31;
        float acc = d0b[o] + d0w[o]
                  + vel[n*3+0] * d0w[32 + o]
                  + vel[n*3+1] * d0w[64 + o]
                  + vel[n*3+2] * d0w[96 + o];
        x1[n*96 + 64 + o] = acc;
    }
}

__global__ __launch_bounds__(256) void gather3_kernel(
    const int* __restrict__ order,
    const int* __restrict__ cnt, const int* __restrict__ nidx,
    const int* __restrict__ ncell, const float* __restrict__ ncoef,
    const float* __restrict__ Y,
    const float* __restrict__ cb3, const float* __restrict__ db3,
    float* __restrict__ out)
{
    int lb = (blockIdx.x & 7) * (gridDim.x >> 3) + (blockIdx.x >> 3);
    int gw = lb * 4 + ((int)threadIdx.x >> 6);
    int lane = threadIdx.x & 63;
    if (gw >= NQ) return;
    int n = order[gw];
    int cn = cnt[n];
    float a0 = 0.f, a1 = 0.f, a2 = 0.f;
#pragma unroll
    for (int seg = 0; seg < 2; ++seg) {
        int kidx = seg * 64 + lane;
        if (kidx < cn) {
            int j  = nidx [n*K + kidx];
            int cb = ncell[n*K + kidx];
            const float* cf = ncoef + (size_t)(n*K + kidx) * 8;
            const float* Yj = Y + (size_t)j * 195;
#pragma unroll
            for (int c = 0; c < 8; ++c) {
                int cell = cb + (c & 1)*16 + ((c >> 1) & 1)*4 + (c >> 2);
                float wgt = cf[c];
                const float* Tp = Yj + cell*3;
                a0 += wgt * Tp[0];
                a1 += wgt * Tp[1];
                a2 += wgt * Tp[2];
            }
        }
    }
#pragma unroll
    for (int s = 32; s > 0; s >>= 1) {
        a0 += __shfl_down(a0, s);
        a1 += __shfl_down(a1, s);
        a2 += __shfl_down(a2, s);
    }
    if (lane == 0) {
        const float* Yn = Y + (size_t)n * 195 + 192;   // dense skip (c=64)
        out[n*3+0] = (a0 + Yn[0] + cb3[0] + db3[0]) * (1.f/128.f);
        out[n*3+1] = (a1 + Yn[1] + cb3[1] + db3[1]) * (1.f/128.f);
        out[n*3+2] = (a2 + Yn[2] + cb3[2] + db3[2]) * (1.f/128.f);
    }
}

} // namespace

extern "C" void kernel_launch(void* const* d_in, const int* in_sizes, int n_in,
                              void* d_out, int out_size, void* d_ws, size_t ws_size,
                              hipStream_t stream)
{
    const float* pos       = (const float*)d_in[0];
    const float* vel       = (const float*)d_in[1];
    const float* box       = (const float*)d_in[2];
    const float* box_feats = (const float*)d_in[3];
    const float* cf_w = (const float*)d_in[4];  const float* cf_b = (const float*)d_in[5];
    const float* co_w = (const float*)d_in[6];  const float* co_b = (const float*)d_in[7];
    const float* d0_w = (const float*)d_in[8];  const float* d0_b = (const float*)d_in[9];
    const float* c1_w = (const float*)d_in[10]; const float* c1_b = (const float*)d_in[11];
    const float* d1_w = (const float*)d_in[12]; const float* d1_b = (const float*)d_in[13];
    const float* c2_w = (const float*)d_in[14]; const float* c2_b = (const float*)d_in[15];
    const float* d2_w = (const float*)d_in[16]; const float* d2_b = (const float*)d_in[17];
    const float* c3_w = (const float*)d_in[18]; const float* c3_b = (const float*)d_in[19];
    const float* d3_w = (const float*)d_in[20]; const float* d3_b = (const float*)d_in[21];

    char* wsb = (char*)d_ws;
    size_t off = 0;
    auto alloc = [&](size_t bytes) {
        void* p = wsb + off;
        off = (off + bytes + 255) & ~(size_t)255;
        return p;
    };
    // Big region time-shared: {f_d2,b_d2} during nn -> {S_cf,S_co} (layer 0)
    // -> bf16 G rows for layers 1/2.
    char*  Graw = (char*)alloc((size_t)NQ * NO * 2 + 4096);   // 50 MB
    unsigned short* G = (unsigned short*)Graw;
    float* f_d2 = (float*)Graw;
    float* b_d2 = (float*)Graw + (size_t)NQ * K;
    float* S_cf = (float*)Graw;                      // [NQ,256] fp32
    float* S_co = (float*)Graw + (size_t)NQ * 256;   // [NQ,192] fp32
    int*   f_cnt  = (int*)  alloc((size_t)NQ * 4);
    int*   f_idx  = (int*)  alloc((size_t)NQ * K * 4);
    int*   f_cell = (int*)  alloc((size_t)NQ * K * 4);
    float* f_coef = (float*)alloc((size_t)NQ * K * 8 * 4);
    int*   b_cnt  = (int*)  alloc((size_t)NQ * 4);
    int*   b_idx  = (int*)  alloc((size_t)NQ * K * 4);
    int*   b_cell = (int*)  alloc((size_t)NQ * K * 4);
    float* b_coef = (float*)alloc((size_t)NQ * K * 8 * 4);
    float* ff     = (float*)alloc((size_t)NQ * 4 * 4);
    float* x1     = (float*)alloc((size_t)NQ * 96 * 4);
    float* x2     = (float*)alloc((size_t)NQ * 64 * 4);
    unsigned short* Bt1 = (unsigned short*)alloc((size_t)NO * 96 * 2);  // 0.8 MB
    unsigned short* Bt2 = (unsigned short*)alloc((size_t)NO * 64 * 2);  // 0.5 MB
    float* W3p    = (float*)alloc((size_t)64 * 195 * 4);
    float* Y      = (float*)alloc((size_t)NQ * 195 * 4);
    // grid structures
    int*   gcnt   = (int*)  alloc((size_t)2 * NC * 4);
    int*   gs_f   = (int*)  alloc((size_t)(NC + 1) * 4);
    int*   gs_b   = (int*)  alloc((size_t)(NC + 1) * 4);
    int*   cur_f  = (int*)  alloc((size_t)NC * 4);
    int*   cur_b  = (int*)  alloc((size_t)NC * 4);
    float* spf    = (float*)alloc((size_t)NQ * 3 * 4);
    int*   sif    = (int*)  alloc((size_t)NQ * 4);
    float* spb    = (float*)alloc((size_t)NB * 3 * 4);
    int*   sib    = (int*)  alloc((size_t)NB * 4);

    dim3 b256(256);
    hipMemsetAsync(gcnt, 0, (size_t)2 * NC * 4, stream);
    prep_kernel<<<512, b256, 0, stream>>>(c1_w, d1_w, c2_w, d2_w, c3_w, d3_w,
                                          pos, box, vel, d0_w, d0_b,
                                          Bt1, Bt2, W3p, ff, x1, gcnt);
    scan_kernel<<<1, 512, 0, stream>>>(gcnt, gs_f, gs_b, cur_f, cur_b);
    scatter_pts_kernel<<<(NQ + NB + 255)/256, b256, 0, stream>>>(
        pos, box, cur_f, cur_b, spf, sif, spb, sib);
    nn2gc_kernel<<<(2*NQ*64 + 255)/256, b256, 0, stream>>>(
        pos, spf, sif, gs_f, spb, sib, gs_b,
        f_cnt, f_idx, f_d2, f_cell, f_coef,
        b_cnt, b_idx, b_d2, b_cell, b_coef);
    // ---- layer 0: merged scatters + dual GEMM (bias fused) ----
    scatter0_kernel<<<2*((NQ+3)/4), b256, 0, stream>>>(
        ff, f_cnt, f_idx, f_cell, f_coef,
        box_feats, b_cnt, b_idx, b_cell, b_coef, S_cf, S_co);
    gemm0_kernel<<<dim3((NQ+127)/128, 2), b256, 0, stream>>>(
        S_co, S_cf, co_w, cf_w, co_b, cf_b, x1, NQ);
    // ---- layer 1: G1 = relu(x1) x [c1;d1] (MFMA) ; x2 = gather(G1) + biases --
    gemmGm_kernel<96><<<dim3((NQ+63)/64, NO/64), b256, 0, stream>>>(x1, Bt1, G, NQ);
    gatherG_kernel<0><<<NBLK8, b256, 0, stream>>>(sif, f_cnt, f_idx, f_cell, f_coef,
        G, c1_b, d1_b, nullptr, x2, nullptr, nullptr);
    // ---- layer 2: G2 = relu(x2) x [c2;d2] (MFMA) ;
    //      fused: x3 = gather + biases + x2 ; Y = relu(x3) * [c3;d3] ----
    gemmGm_kernel<64><<<dim3((NQ+63)/64, NO/64), b256, 0, stream>>>(x2, Bt2, G, NQ);
    gatherG_kernel<1><<<NBLK8, b256, 0, stream>>>(sif, f_cnt, f_idx, f_cell, f_coef,
        G, c2_b, d2_b, x2, nullptr, W3p, Y);
    // ---- layer 3 gather (O=3) ----
    gather3_kernel<<<NBLK8, b256, 0, stream>>>(sif, f_cnt, f_idx, f_cell, f_coef,
        Y, c3_b, d3_b, (float*)d_out);

    (void)in_sizes; (void)n_in; (void)out_size; (void)ws_size;
    (void)f_d2; (void)b_d2;
}